// Round 1
// baseline (6978.735 us; speedup 1.0000x reference)
//
#include <hip/hip_runtime.h>
#include <hip/hip_bf16.h>
#include <cstdint>

#define DDAYS 5
#define TT 8192
#define FF 768
#define HH 64
#define GG 256  // 4*H

__device__ __forceinline__ float fast_tanh(float x) {
    return 1.f - 2.f / (__expf(2.f * x) + 1.f);
}
__device__ __forceinline__ float fast_sig(float x) {
    return 1.f / (1.f + __expf(-x));
}

// ---------------------------------------------------------------------------
// Kernel 1: ux[m][g] = sum_f A[m][f] * B[g][f]   (bias added later in scan)
// A = text_input [40960][768], B = U_all_w [256][768], C = ux [40960][256]
// 128x128 tile, 256 threads, 8x8 per thread, K-tile 16.
// ---------------------------------------------------------------------------
__global__ __launch_bounds__(256, 2) void gemm_ux(
    const float* __restrict__ A, const float* __restrict__ B,
    float* __restrict__ C)
{
    __shared__ __align__(16) float As[16][132];
    __shared__ __align__(16) float Bs[16][132];
    const int tid = threadIdx.x;
    const int m0 = blockIdx.x * 128;
    const int n0 = blockIdx.y * 128;
    const int tx = tid & 15, ty = tid >> 4;
    const int i0 = tx * 8, j0 = ty * 8;
    const int lrow = tid >> 2, lc4 = tid & 3;

    const float* Ap = A + (size_t)(m0 + lrow) * FF + lc4 * 4;
    const float* Bp = B + (size_t)(n0 + lrow) * FF + lc4 * 4;

    float4 pa0 = *(const float4*)(Ap);
    float4 pa1 = *(const float4*)(Ap + 64 * FF);
    float4 pb0 = *(const float4*)(Bp);
    float4 pb1 = *(const float4*)(Bp + 64 * FF);

    float acc[8][8] = {};

    for (int kt = 0; kt < FF / 16; ++kt) {
        __syncthreads();
        {
            const int kk = lc4 * 4;
            As[kk + 0][lrow] = pa0.x; As[kk + 1][lrow] = pa0.y;
            As[kk + 2][lrow] = pa0.z; As[kk + 3][lrow] = pa0.w;
            As[kk + 0][lrow + 64] = pa1.x; As[kk + 1][lrow + 64] = pa1.y;
            As[kk + 2][lrow + 64] = pa1.z; As[kk + 3][lrow + 64] = pa1.w;
            Bs[kk + 0][lrow] = pb0.x; Bs[kk + 1][lrow] = pb0.y;
            Bs[kk + 2][lrow] = pb0.z; Bs[kk + 3][lrow] = pb0.w;
            Bs[kk + 0][lrow + 64] = pb1.x; Bs[kk + 1][lrow + 64] = pb1.y;
            Bs[kk + 2][lrow + 64] = pb1.z; Bs[kk + 3][lrow + 64] = pb1.w;
        }
        __syncthreads();
        if (kt + 1 < FF / 16) {
            const int k0 = (kt + 1) * 16;
            pa0 = *(const float4*)(Ap + k0);
            pa1 = *(const float4*)(Ap + 64 * FF + k0);
            pb0 = *(const float4*)(Bp + k0);
            pb1 = *(const float4*)(Bp + 64 * FF + k0);
        }
#pragma unroll
        for (int k = 0; k < 16; ++k) {
            float a[8], b[8];
            *(float4*)&a[0] = *(const float4*)&As[k][i0];
            *(float4*)&a[4] = *(const float4*)&As[k][i0 + 4];
            *(float4*)&b[0] = *(const float4*)&Bs[k][j0];
            *(float4*)&b[4] = *(const float4*)&Bs[k][j0 + 4];
#pragma unroll
            for (int r = 0; r < 8; ++r)
#pragma unroll
                for (int c = 0; c < 8; ++c)
                    acc[r][c] = fmaf(a[r], b[c], acc[r][c]);
        }
    }
#pragma unroll
    for (int r = 0; r < 8; ++r) {
        float4 s0 = make_float4(acc[r][0], acc[r][1], acc[r][2], acc[r][3]);
        float4 s1 = make_float4(acc[r][4], acc[r][5], acc[r][6], acc[r][7]);
        float* Cp = C + (size_t)(m0 + i0 + r) * GG + n0 + j0;
        *(float4*)Cp = s0;
        *(float4*)(Cp + 4) = s1;
    }
}

// ---------------------------------------------------------------------------
// Kernel 2: sequential TimeLSTM scan, one block per day (256 thr = 4 waves).
// Thread tid holds W_all row tid (64 regs) and a quarter of W_d row tid>>2.
// h/c kept as per-wave LDS copies; gates ping-pong -> ONE barrier per step.
// Writes y[d][t][j] = tanh(sigmoid(o_pre)) and final h.
// ---------------------------------------------------------------------------
__global__ __launch_bounds__(256) void scan_kernel(
    const float* __restrict__ ux, const float* __restrict__ ts,
    const float* __restrict__ Ww, const float* __restrict__ Wb,
    const float* __restrict__ Ub,
    const float* __restrict__ Dw, const float* __restrict__ Db,
    float* __restrict__ y, float* __restrict__ hfin)
{
    const int d = blockIdx.x;
    const int tid = threadIdx.x;
    const int wv = tid >> 6;
    const int lane = tid & 63;

    float wall[64];
#pragma unroll
    for (int k = 0; k < 16; k++) {
        float4 v = *(const float4*)&Ww[tid * 64 + 4 * k];
        wall[4 * k] = v.x; wall[4 * k + 1] = v.y;
        wall[4 * k + 2] = v.z; wall[4 * k + 3] = v.w;
    }
    const float bias = Wb[tid] + Ub[tid];

    const int jrow = tid >> 2, q = tid & 3;
    float wd[16];
#pragma unroll
    for (int k = 0; k < 4; k++) {
        float4 v = *(const float4*)&Dw[jrow * 64 + q * 16 + 4 * k];
        wd[4 * k] = v.x; wd[4 * k + 1] = v.y;
        wd[4 * k + 2] = v.z; wd[4 * k + 3] = v.w;
    }
    const float wdb = Db[jrow];

    __shared__ __align__(16) float h_s[4][64];
    __shared__ __align__(16) float c_s[4][64];
    __shared__ float gates[2][256];
    __shared__ float cs1_s[2][64];

    h_s[wv][lane] = 0.f;
    c_s[wv][lane] = 0.f;
    __syncthreads();

    const float* uxd = ux + (size_t)d * TT * GG;
    const float* tsd = ts + (size_t)d * TT;
    float* yd = y + (size_t)d * TT * HH;
    const int gt = wv;

    float u0 = uxd[tid];
    float u1 = uxd[GG + tid];
    float tv0 = tsd[0];
    float tv1 = tsd[1];

    for (int t = 0; t < TT; ++t) {
        const int buf = t & 1;
        const int tn = (t + 2 < TT) ? t + 2 : TT - 1;
        float u2 = uxd[(size_t)tn * GG + tid];
        float tv2 = tsd[tn];

        // gate pre-activation: dot64(h, W_all[tid]) + bias + u
        float a0 = 0.f, a1 = 0.f, a2 = 0.f, a3 = 0.f;
#pragma unroll
        for (int k = 0; k < 64; k += 4) {
            float4 h4 = *(const float4*)&h_s[wv][k];
            a0 = fmaf(h4.x, wall[k], a0);
            a1 = fmaf(h4.y, wall[k + 1], a1);
            a2 = fmaf(h4.z, wall[k + 2], a2);
            a3 = fmaf(h4.w, wall[k + 3], a3);
        }
        float pre = (a0 + a1) + (a2 + a3) + bias + u0;

        // W_d partial: quarter dot of c
        float p0 = 0.f, p1 = 0.f;
#pragma unroll
        for (int k = 0; k < 16; k += 4) {
            float4 c4 = *(const float4*)&c_s[wv][q * 16 + k];
            p0 = fmaf(c4.x, wd[k], p0);
            p1 = fmaf(c4.y, wd[k + 1], p1);
            p0 = fmaf(c4.z, wd[k + 2], p0);
            p1 = fmaf(c4.w, wd[k + 3], p1);
        }
        float p = p0 + p1;
        p += __shfl_xor(p, 1);
        p += __shfl_xor(p, 2);

        float gv = (gt == 3) ? fast_tanh(pre) : fast_sig(pre);
        gates[buf][tid] = gv;
        if (q == 0) cs1_s[buf][jrow] = fast_tanh(p + wdb);
        if (gt == 2) yd[(size_t)t * HH + lane] = fast_tanh(gv);

        __syncthreads();

        // state update (all waves redundantly on their own h/c copy)
        float co = c_s[wv][lane];
        float cs1 = cs1_s[buf][lane];
        float cadj = co - cs1 + cs1 * tv0;
        float fg = gates[buf][lane];
        float ig = gates[buf][64 + lane];
        float og = gates[buf][128 + lane];
        float gg2 = gates[buf][192 + lane];
        float cn = fg * cadj + ig * gg2;
        float hn = og * fast_tanh(cn);
        c_s[wv][lane] = cn;
        h_s[wv][lane] = hn;

        u0 = u1; u1 = u2; tv0 = tv1; tv1 = tv2;
    }
    if (tid < 64) hfin[d * 64 + tid] = h_s[0][tid];
}

// ---------------------------------------------------------------------------
// Kernel 3: score[d][t] = V . tanh(q_d + W2 y_dt + b2) + Vb
// q_d = W1 h_fin[d] + b1 computed per block.  One wave per t, TW t's each.
// ---------------------------------------------------------------------------
#define TW 32
__global__ __launch_bounds__(256) void score_kernel(
    const float* __restrict__ y, const float* __restrict__ hfin,
    const float* __restrict__ W1, const float* __restrict__ b1,
    const float* __restrict__ W2, const float* __restrict__ b2,
    const float* __restrict__ Vw, const float* __restrict__ Vb,
    float* __restrict__ score)
{
    const int d = blockIdx.y;
    const int tid = threadIdx.x;
    const int lane = tid & 63, wv = tid >> 6;
    __shared__ __align__(16) float hf[64];
    __shared__ float qs[64];
    if (tid < 64) hf[tid] = hfin[d * 64 + tid];
    __syncthreads();
    if (tid < 64) {
        float acc = b1[tid];
#pragma unroll
        for (int k = 0; k < 16; k++) {
            float4 w = *(const float4*)&W1[tid * 64 + 4 * k];
            float4 h4 = *(const float4*)&hf[4 * k];
            acc += w.x * h4.x + w.y * h4.y + w.z * h4.z + w.w * h4.w;
        }
        qs[tid] = acc;
    }
    __syncthreads();

    float w2[64];
#pragma unroll
    for (int k = 0; k < 16; k++) {
        float4 v = *(const float4*)&W2[lane * 64 + 4 * k];
        w2[4 * k] = v.x; w2[4 * k + 1] = v.y;
        w2[4 * k + 2] = v.z; w2[4 * k + 3] = v.w;
    }
    const float qb = qs[lane] + b2[lane];
    const float vr = Vw[lane];
    const float vb = Vb[0];
    const int tbase = blockIdx.x * (4 * TW) + wv * TW;
    const float* yd = y + (size_t)d * TT * HH;

    for (int i = 0; i < TW; i++) {
        const int t = tbase + i;
        const float* yrow = yd + (size_t)t * HH;
        float a0 = 0.f, a1 = 0.f, a2 = 0.f, a3 = 0.f;
#pragma unroll
        for (int k = 0; k < 64; k += 4) {
            float4 yv = *(const float4*)&yrow[k];
            a0 = fmaf(yv.x, w2[k], a0);
            a1 = fmaf(yv.y, w2[k + 1], a1);
            a2 = fmaf(yv.z, w2[k + 2], a2);
            a3 = fmaf(yv.w, w2[k + 3], a3);
        }
        float v = fast_tanh(qb + (a0 + a1) + (a2 + a3));
        float s = v * vr;
#pragma unroll
        for (int off = 32; off > 0; off >>= 1) s += __shfl_xor(s, off);
        if (lane == 0) score[(size_t)d * TT + t] = s + vb;
    }
}

// ---------------------------------------------------------------------------
// Kernel 4: per-day softmax over T + ctx[d][j] = sum_t attn * y
// ---------------------------------------------------------------------------
__global__ __launch_bounds__(256) void ctx_kernel(
    const float* __restrict__ score, const float* __restrict__ y,
    float* __restrict__ ctx)
{
    const int d = blockIdx.x;
    const int tid = threadIdx.x;
    __shared__ float red[256];
    const float* sc = score + (size_t)d * TT;

    float m = -1e30f;
    for (int t = tid; t < TT; t += 256) m = fmaxf(m, sc[t]);
    red[tid] = m; __syncthreads();
    for (int s = 128; s > 0; s >>= 1) {
        if (tid < s) red[tid] = fmaxf(red[tid], red[tid + s]);
        __syncthreads();
    }
    m = red[0]; __syncthreads();

    float se = 0.f;
    for (int t = tid; t < TT; t += 256) se += __expf(sc[t] - m);
    red[tid] = se; __syncthreads();
    for (int s = 128; s > 0; s >>= 1) {
        if (tid < s) red[tid] += red[tid + s];
        __syncthreads();
    }
    const float inv = 1.f / red[0];
    __syncthreads();

    const int j = tid & 63, grp = tid >> 6;
    const float* yd = y + (size_t)d * TT * HH;
    float a = 0.f;
    for (int t = grp; t < TT; t += 4)
        a = fmaf(__expf(sc[t] - m), yd[(size_t)t * HH + j], a);
    red[tid] = a; __syncthreads();
    if (tid < 64)
        ctx[d * 64 + tid] =
            (red[tid] + red[tid + 64] + red[tid + 128] + red[tid + 192]) * inv;
}

// ---------------------------------------------------------------------------
// Kernel 5: day LSTM (1 step) + day attention + stock head -> out[1]
// 320 threads = 5 waves (one per day for the score2 phase).
// ---------------------------------------------------------------------------
__global__ __launch_bounds__(320) void final_kernel(
    const float* __restrict__ ctx,
    const float* __restrict__ Wih, const float* __restrict__ bih,
    const float* __restrict__ bhh,
    const float* __restrict__ W1, const float* __restrict__ b1,
    const float* __restrict__ W2, const float* __restrict__ b2,
    const float* __restrict__ Vw, const float* __restrict__ Vb,
    const float* __restrict__ stw, const float* __restrict__ stb,
    float* __restrict__ out)
{
    const int tid = threadIdx.x;
    const int dd = tid >> 6, j = tid & 63;
    __shared__ __align__(16) float ctxs[320];
    __shared__ float gsh[5 * 256];
    __shared__ __align__(16) float fulls[320];
    __shared__ __align__(16) float lasts[320];
    __shared__ float s2[5];

    ctxs[tid] = ctx[tid];
    __syncthreads();

    if (tid < 256) {
        float w[64];
#pragma unroll
        for (int k = 0; k < 16; k++) {
            float4 v = *(const float4*)&Wih[tid * 64 + 4 * k];
            w[4 * k] = v.x; w[4 * k + 1] = v.y;
            w[4 * k + 2] = v.z; w[4 * k + 3] = v.w;
        }
        const float bb = bih[tid] + bhh[tid];
        for (int dday = 0; dday < 5; ++dday) {
            float acc = bb;
#pragma unroll
            for (int k = 0; k < 64; k += 4) {
                float4 c4 = *(const float4*)&ctxs[dday * 64 + k];
                acc += w[k] * c4.x + w[k + 1] * c4.y + w[k + 2] * c4.z +
                       w[k + 3] * c4.w;
            }
            gsh[dday * 256 + tid] = acc;
        }
    }
    __syncthreads();
    {
        float gi = gsh[dd * 256 + j];
        float gg2 = gsh[dd * 256 + 128 + j];
        float go = gsh[dd * 256 + 192 + j];
        float c = fast_sig(gi) * fast_tanh(gg2);
        float hd = fast_sig(go) * fast_tanh(c);
        lasts[tid] = hd;
        fulls[tid] = fast_tanh(hd);
    }
    __syncthreads();
    {
        float w1r[64], w2r[64];
#pragma unroll
        for (int k = 0; k < 16; k++) {
            float4 v1 = *(const float4*)&W1[j * 64 + 4 * k];
            float4 v2 = *(const float4*)&W2[j * 64 + 4 * k];
            w1r[4 * k] = v1.x; w1r[4 * k + 1] = v1.y;
            w1r[4 * k + 2] = v1.z; w1r[4 * k + 3] = v1.w;
            w2r[4 * k] = v2.x; w2r[4 * k + 1] = v2.y;
            w2r[4 * k + 2] = v2.z; w2r[4 * k + 3] = v2.w;
        }
        float acc = b1[j] + b2[j];
#pragma unroll
        for (int k = 0; k < 64; ++k)
            acc += w1r[k] * lasts[dd * 64 + k] + w2r[k] * fulls[dd * 64 + k];
        float v = fast_tanh(acc) * Vw[j];
#pragma unroll
        for (int off = 32; off > 0; off >>= 1) v += __shfl_xor(v, off);
        if (j == 0) s2[dd] = v + Vb[0];
    }
    __syncthreads();
    if (tid < 64) {
        float m = s2[0];
#pragma unroll
        for (int dday = 1; dday < 5; ++dday) m = fmaxf(m, s2[dday]);
        float se = 0.f, ft = 0.f;
#pragma unroll
        for (int dday = 0; dday < 5; ++dday) {
            float e = __expf(s2[dday] - m);
            se += e;
            ft += e * fulls[dday * 64 + tid];
        }
        ft /= se;
        float pv = ft * stw[tid];
#pragma unroll
        for (int off = 32; off > 0; off >>= 1) pv += __shfl_xor(pv, off);
        if (tid == 0) out[0] = 3.f * fast_tanh(pv + stb[0]);
    }
}

// ---------------------------------------------------------------------------
extern "C" void kernel_launch(void* const* d_in, const int* in_sizes, int n_in,
                              void* d_out, int out_size, void* d_ws,
                              size_t ws_size, hipStream_t stream)
{
    const float* x     = (const float*)d_in[0];
    const float* ts    = (const float*)d_in[1];
    const float* Wallw = (const float*)d_in[3];
    const float* Wallb = (const float*)d_in[4];
    const float* Uallw = (const float*)d_in[5];
    const float* Uallb = (const float*)d_in[6];
    const float* Wdw   = (const float*)d_in[7];
    const float* Wdb   = (const float*)d_in[8];
    const float* taW1w = (const float*)d_in[9];
    const float* taW1b = (const float*)d_in[10];
    const float* taW2w = (const float*)d_in[11];
    const float* taW2b = (const float*)d_in[12];
    const float* taVw  = (const float*)d_in[13];
    const float* taVb  = (const float*)d_in[14];
    const float* Wih   = (const float*)d_in[15];
    const float* bih   = (const float*)d_in[17];
    const float* bhh   = (const float*)d_in[18];
    const float* daW1w = (const float*)d_in[19];
    const float* daW1b = (const float*)d_in[20];
    const float* daW2w = (const float*)d_in[21];
    const float* daW2b = (const float*)d_in[22];
    const float* daVw  = (const float*)d_in[23];
    const float* daVb  = (const float*)d_in[24];
    const float* stw   = (const float*)d_in[25];
    const float* stb   = (const float*)d_in[26];
    float* out = (float*)d_out;

    float* ux = (float*)d_ws;                       // [5][8192][256]
    float* yb = ux + (size_t)DDAYS * TT * GG;       // [5][8192][64]
    float* sc = yb + (size_t)DDAYS * TT * HH;       // [5][8192]
    float* hf = sc + (size_t)DDAYS * TT;            // [5][64]
    float* cx = hf + 512;                           // [5][64]

    gemm_ux<<<dim3(320, 2), 256, 0, stream>>>(x, Uallw, ux);
    scan_kernel<<<dim3(DDAYS), 256, 0, stream>>>(ux, ts, Wallw, Wallb, Uallb,
                                                 Wdw, Wdb, yb, hf);
    score_kernel<<<dim3(TT / (4 * TW), DDAYS), 256, 0, stream>>>(
        yb, hf, taW1w, taW1b, taW2w, taW2b, taVw, taVb, sc);
    ctx_kernel<<<dim3(DDAYS), 256, 0, stream>>>(sc, yb, cx);
    final_kernel<<<dim3(1), 320, 0, stream>>>(cx, Wih, bih, bhh, daW1w, daW1b,
                                              daW2w, daW2b, daVw, daVb, stw,
                                              stb, out);
}